// Round 3
// baseline (108.111 us; speedup 1.0000x reference)
//
#include <hip/hip_runtime.h>

// Focal loss, mean-reduced. inputs: [B,T,2] f32; targets: [B,T] int32 (0/1).
// B=T=4096. out: 1 float (mean over B*T*2 elements).

constexpr unsigned NPOS    = 4096u * 4096u;            // B*T positions
constexpr int      BLOCKS  = 2048;
constexpr int      THREADS = 256;
constexpr unsigned NF4     = NPOS / 2;                 // float4 count (2 pos each)
constexpr unsigned STRIDE  = (unsigned)BLOCKS * THREADS;   // 524288
constexpr int      ITERS   = (int)(NF4 / STRIDE);          // exactly 16
constexpr int      GROUP   = 8;                        // staged loads per group

// g(z) = (1 - sigma(z))^2 * (-log sigma(z)) ; sigma(z) = 1/(1+exp(-z))
// element (x, ts): ts==1 -> ALPHA * g(x) ; ts==0 -> (1-ALPHA) * g(-x)
__device__ __forceinline__ float g_of(float z) {
    float e   = __expf(-z);
    float u   = 1.f + e;
    float pt  = __builtin_amdgcn_rcpf(u);   // sigma(z)
    float bce = __logf(u);                  // -log sigma(z)
    float om  = e * pt;                     // 1 - sigma(z), no cancellation
    return om * om * bce;
}

__global__ __launch_bounds__(THREADS, 4) void focal_fused(
    const float4* __restrict__ in4,    // [NF4] : one float4 = positions 2i, 2i+1
    const int2*   __restrict__ tg2,    // [NF4] : targets for positions 2i, 2i+1
    float*        __restrict__ partial,   // [BLOCKS]
    unsigned*     __restrict__ cnt,       // zeroed per call via hipMemsetAsync
    float*        __restrict__ out)
{
    const unsigned tid = blockIdx.x * (unsigned)THREADS + threadIdx.x;

    float acc_t = 0.f;   // true-class terms  (weight 0.25)
    float acc_f = 0.f;   // false-class terms (weight 0.75)

#pragma unroll
    for (int grp = 0; grp < ITERS / GROUP; ++grp) {
        float4 v[GROUP];
        int2   t[GROUP];
        // load phase — every instruction lane-contiguous (dense 1KB/wave)
#pragma unroll
        for (int j = 0; j < GROUP; ++j) {
            unsigned idx = (unsigned)(grp * GROUP + j) * STRIDE + tid;
            v[j] = in4[idx];
            t[j] = tg2[idx];
        }
        // compute phase
#pragma unroll
        for (int j = 0; j < GROUP; ++j) {
            {   // position 2idx
                bool  one = t[j].x != 0;
                float xt  = one ? v[j].y : v[j].x;
                float xf  = one ? v[j].x : v[j].y;
                acc_t += g_of(xt);
                acc_f += g_of(-xf);
            }
            {   // position 2idx+1
                bool  one = t[j].y != 0;
                float xt  = one ? v[j].w : v[j].z;
                float xf  = one ? v[j].z : v[j].w;
                acc_t += g_of(xt);
                acc_f += g_of(-xf);
            }
        }
    }

    float acc = 0.25f * acc_t + 0.75f * acc_f;

    // wave (64-lane) reduction
#pragma unroll
    for (int off = 32; off > 0; off >>= 1)
        acc += __shfl_down(acc, off, 64);

    __shared__ float sm[THREADS / 64];
    __shared__ bool  amLast;
    const int lane = threadIdx.x & 63;
    const int wid  = threadIdx.x >> 6;
    if (lane == 0) sm[wid] = acc;
    __syncthreads();

    if (threadIdx.x == 0) {
        float s = 0.f;
#pragma unroll
        for (int w = 0; w < THREADS / 64; ++w) s += sm[w];
        partial[blockIdx.x] = s;
        __threadfence();                         // release: partial visible device-wide
        unsigned old = atomicAdd(cnt, 1u);       // device-scope
        amLast = (old == (unsigned)(BLOCKS - 1));
    }
    __syncthreads();

    if (amLast) {
        __threadfence();                         // acquire: see all partials
        float s = 0.f;
        for (int i = threadIdx.x; i < BLOCKS; i += THREADS)
            s += partial[i];                     // fixed order -> deterministic
#pragma unroll
        for (int off = 32; off > 0; off >>= 1)
            s += __shfl_down(s, off, 64);
        if (lane == 0) sm[wid] = s;
        __syncthreads();
        if (threadIdx.x == 0) {
            float tot = sm[0] + sm[1] + sm[2] + sm[3];
            out[0] = tot * (1.0f / (2.0f * (float)NPOS));
        }
    }
}

extern "C" void kernel_launch(void* const* d_in, const int* in_sizes, int n_in,
                              void* d_out, int out_size, void* d_ws, size_t ws_size,
                              hipStream_t stream) {
    const float4* in4 = (const float4*)d_in[0];
    const int2*   tg2 = (const int2*)d_in[1];
    float*    partial = (float*)d_ws;
    unsigned* cnt     = (unsigned*)((char*)d_ws + BLOCKS * sizeof(float));
    float*    out     = (float*)d_out;

    hipMemsetAsync(cnt, 0, sizeof(unsigned), stream);   // capture-legal memset node
    focal_fused<<<BLOCKS, THREADS, 0, stream>>>(in4, tg2, partial, cnt, out);
}

// Round 4
// 54.325 us; speedup vs baseline: 1.9901x; 1.9901x over previous
//
#include <hip/hip_runtime.h>

// Focal loss, mean-reduced. inputs: [B,T,2] f32; targets: [B,T] int32 (0/1).
// B=T=4096. out: 1 float (mean over B*T*2 elements).

constexpr unsigned NPOS    = 4096u * 4096u;              // B*T positions
constexpr int      BLOCKS  = 2048;
constexpr int      THREADS = 256;
constexpr unsigned NQUAD   = NPOS / 4;                   // 4 positions / iter
constexpr unsigned STRIDE  = (unsigned)BLOCKS * THREADS; // 524288
constexpr int      ITERS   = (int)(NQUAD / STRIDE);      // exactly 8

// g(z) = (1 - sigma(z))^2 * (-log sigma(z)) ; sigma(z) = 1/(1+exp(-z))
// element (x, ts): ts==1 -> ALPHA * g(x) ; ts==0 -> (1-ALPHA) * g(-x)
__device__ __forceinline__ float g_of(float z) {
    float e   = __expf(-z);
    float u   = 1.f + e;
    float pt  = __builtin_amdgcn_rcpf(u);   // sigma(z)
    float bce = __logf(u);                  // -log sigma(z)
    float om  = e * pt;                     // 1 - sigma(z), no cancellation
    return om * om * bce;
}

__global__ __launch_bounds__(THREADS, 4) void focal_fused(
    const float4* __restrict__ in,     // float4 = 2 positions (interleaved classes)
    const int4*   __restrict__ tgt,    // int4   = 4 positions
    float*        __restrict__ partial,   // [BLOCKS] in d_ws
    unsigned*     __restrict__ cnt,       // zeroed per call via hipMemsetAsync
    float*        __restrict__ out)
{
    const unsigned tid = blockIdx.x * (unsigned)THREADS + threadIdx.x;

    float acc_t = 0.f;   // true-class terms  (weight 0.25)
    float acc_f = 0.f;   // false-class terms (weight 0.75)

#pragma unroll
    for (int i = 0; i < ITERS; ++i) {
        unsigned q  = tid + (unsigned)i * STRIDE;
        float4   v0 = in[2u * q];
        float4   v1 = in[2u * q + 1u];
        int4     t4 = tgt[q];

        float x0[4] = {v0.x, v0.z, v1.x, v1.z};   // class-0 logits
        float x1[4] = {v0.y, v0.w, v1.y, v1.w};   // class-1 logits
        int   tt[4] = {t4.x, t4.y, t4.z, t4.w};

#pragma unroll
        for (int p = 0; p < 4; ++p) {
            bool  one = tt[p] != 0;
            float xt  = one ? x1[p] : x0[p];      // true-class logit
            float xf  = one ? x0[p] : x1[p];      // false-class logit
            acc_t += g_of(xt);
            acc_f += g_of(-xf);
        }
    }

    float acc = 0.25f * acc_t + 0.75f * acc_f;

    // wave (64-lane) reduction
#pragma unroll
    for (int off = 32; off > 0; off >>= 1)
        acc += __shfl_down(acc, off, 64);

    __shared__ float sm[THREADS / 64];
    __shared__ bool  amLast;
    const int lane = threadIdx.x & 63;
    const int wid  = threadIdx.x >> 6;
    if (lane == 0) sm[wid] = acc;
    __syncthreads();

    if (threadIdx.x == 0) {
        float s = 0.f;
#pragma unroll
        for (int w = 0; w < THREADS / 64; ++w) s += sm[w];
        // Agent-scope write-through store: lands at the device coherence
        // point with NO L2 writeback fence needed.
        __hip_atomic_store(&partial[blockIdx.x], s,
                           __ATOMIC_RELAXED, __HIP_MEMORY_SCOPE_AGENT);
        // Drain the store ack before the arrival atomic -> any observer of
        // the incremented count also observes our partial at the MALL.
        asm volatile("s_waitcnt vmcnt(0)" ::: "memory");
        unsigned old = __hip_atomic_fetch_add(cnt, 1u,
                           __ATOMIC_RELAXED, __HIP_MEMORY_SCOPE_AGENT);
        amLast = (old == (unsigned)(BLOCKS - 1));
    }
    __syncthreads();

    if (amLast) {
        float s = 0.f;
        for (int i = threadIdx.x; i < BLOCKS; i += THREADS)
            s += __hip_atomic_load(&partial[i],
                     __ATOMIC_RELAXED, __HIP_MEMORY_SCOPE_AGENT);  // fixed order
#pragma unroll
        for (int off = 32; off > 0; off >>= 1)
            s += __shfl_down(s, off, 64);
        if (lane == 0) sm[wid] = s;
        __syncthreads();
        if (threadIdx.x == 0) {
            float tot = sm[0] + sm[1] + sm[2] + sm[3];
            out[0] = tot * (1.0f / (2.0f * (float)NPOS));
        }
    }
}

extern "C" void kernel_launch(void* const* d_in, const int* in_sizes, int n_in,
                              void* d_out, int out_size, void* d_ws, size_t ws_size,
                              hipStream_t stream) {
    const float4* in  = (const float4*)d_in[0];
    const int4*   tgt = (const int4*)d_in[1];
    float*    partial = (float*)d_ws;
    unsigned* cnt     = (unsigned*)((char*)d_ws + BLOCKS * sizeof(float));
    float*    out     = (float*)d_out;

    hipMemsetAsync(cnt, 0, sizeof(unsigned), stream);   // capture-legal memset node
    focal_fused<<<BLOCKS, THREADS, 0, stream>>>(in, tgt, partial, cnt, out);
}

// Round 5
// 42.325 us; speedup vs baseline: 2.5543x; 1.2835x over previous
//
#include <hip/hip_runtime.h>

// Focal loss, mean-reduced. inputs: [B,T,2] f32; targets: [B,T] int32 (0/1).
// B=T=4096. out: 1 float (mean over B*T*2 elements).
//
// Structure (R5): two kernels (fused tails measured +15..+69us — reverted).
// Main kernel: all 16 iterations' loads issued up-front (dense, lane-contiguous),
// sched_barrier(0) pins load-phase before compute-phase -> ~32 loads in
// flight per wave, compute drains with counted vmcnt.

constexpr unsigned NPOS    = 4096u * 4096u;               // B*T positions
constexpr int      BLOCKS  = 2048;
constexpr int      THREADS = 256;
constexpr unsigned NF4     = NPOS / 2;                    // float4 count (2 pos each)
constexpr unsigned STRIDE  = (unsigned)BLOCKS * THREADS;  // 524288
constexpr int      ITERS   = (int)(NF4 / STRIDE);         // exactly 16

// g(z) = (1 - sigma(z))^2 * (-log sigma(z)) ; sigma(z) = 1/(1+exp(-z))
// element (x, ts): ts==1 -> ALPHA * g(x) ; ts==0 -> (1-ALPHA) * g(-x)
__device__ __forceinline__ float g_of(float z) {
    float e   = __expf(-z);
    float u   = 1.f + e;
    float pt  = __builtin_amdgcn_rcpf(u);   // sigma(z)
    float bce = __logf(u);                  // -log sigma(z)
    float om  = e * pt;                     // 1 - sigma(z), no cancellation
    return om * om * bce;
}

__global__ __launch_bounds__(THREADS, 4) void focal_partial(
    const float4* __restrict__ in4,    // [NF4] one float4 = positions 2i,2i+1 (x=c0,y=c1,z=c0,w=c1)
    const int2*   __restrict__ tg2,    // [NF4] targets for positions 2i,2i+1
    float*        __restrict__ partial)
{
    const unsigned tid = blockIdx.x * (unsigned)THREADS + threadIdx.x;

    // ---- load phase: every instruction dense (1KB / 512B per wave) ----
    float4 v[ITERS];
    int2   t[ITERS];
#pragma unroll
    for (int i = 0; i < ITERS; ++i) {
        unsigned idx = (unsigned)i * STRIDE + tid;
        v[i] = in4[idx];
        t[i] = tg2[idx];
    }
    __builtin_amdgcn_sched_barrier(0);   // pin: all loads issued before compute

    // ---- compute phase: drains loads in issue order (counted vmcnt) ----
    float acc_t = 0.f;   // true-class terms  (weight 0.25)
    float acc_f = 0.f;   // false-class terms (weight 0.75)
#pragma unroll
    for (int i = 0; i < ITERS; ++i) {
        {   // position 2idx
            bool  one = t[i].x != 0;
            float xt  = one ? v[i].y : v[i].x;
            float xf  = one ? v[i].x : v[i].y;
            acc_t += g_of(xt);
            acc_f += g_of(-xf);
        }
        {   // position 2idx+1
            bool  one = t[i].y != 0;
            float xt  = one ? v[i].w : v[i].z;
            float xf  = one ? v[i].z : v[i].w;
            acc_t += g_of(xt);
            acc_f += g_of(-xf);
        }
    }

    float acc = 0.25f * acc_t + 0.75f * acc_f;

    // wave (64-lane) reduction
#pragma unroll
    for (int off = 32; off > 0; off >>= 1)
        acc += __shfl_down(acc, off, 64);

    __shared__ float sm[THREADS / 64];
    const int lane = threadIdx.x & 63;
    const int wid  = threadIdx.x >> 6;
    if (lane == 0) sm[wid] = acc;
    __syncthreads();
    if (threadIdx.x == 0) {
        float s = 0.f;
#pragma unroll
        for (int w = 0; w < THREADS / 64; ++w) s += sm[w];
        partial[blockIdx.x] = s;
    }
}

__global__ __launch_bounds__(256) void focal_final(
    const float* __restrict__ partial, float* __restrict__ out)
{
    float acc = 0.f;
    for (int i = threadIdx.x; i < BLOCKS; i += 256) acc += partial[i];
#pragma unroll
    for (int off = 32; off > 0; off >>= 1)
        acc += __shfl_down(acc, off, 64);

    __shared__ float sm[4];
    const int lane = threadIdx.x & 63;
    const int wid  = threadIdx.x >> 6;
    if (lane == 0) sm[wid] = acc;
    __syncthreads();
    if (threadIdx.x == 0) {
        float s = sm[0] + sm[1] + sm[2] + sm[3];
        out[0] = s * (1.0f / (2.0f * (float)NPOS));  // mean over B*T*2 elements
    }
}

extern "C" void kernel_launch(void* const* d_in, const int* in_sizes, int n_in,
                              void* d_out, int out_size, void* d_ws, size_t ws_size,
                              hipStream_t stream) {
    const float4* in4 = (const float4*)d_in[0];
    const int2*   tg2 = (const int2*)d_in[1];
    float* partial    = (float*)d_ws;
    float* out        = (float*)d_out;

    focal_partial<<<BLOCKS, THREADS, 0, stream>>>(in4, tg2, partial);
    focal_final<<<1, 256, 0, stream>>>(partial, out);
}

// Round 6
// 38.661 us; speedup vs baseline: 2.7964x; 1.0948x over previous
//
#include <hip/hip_runtime.h>

// Focal loss, mean-reduced. inputs: [B,T,2] f32; targets: [B,T] int32 (0/1).
// B=T=4096. out: 1 float (mean over B*T*2 elements).
//
// R6: best-known R1 loop + explicit depth-2 register pipeline (named regs,
// no sched_barrier, no min-wave cap — R3/R5 showed the compiler defeats
// bulk prefetch; depth-2 is cheap enough for regalloc to keep).

constexpr unsigned NPOS    = 4096u * 4096u;              // B*T positions
constexpr int      BLOCKS  = 2048;
constexpr int      THREADS = 256;
constexpr unsigned NQUAD   = NPOS / 4;                   // 4 positions / iter
constexpr unsigned STRIDE  = (unsigned)BLOCKS * THREADS; // 524288
constexpr int      ITERS   = (int)(NQUAD / STRIDE);      // exactly 8

// g(z) = (1 - sigma(z))^2 * (-log sigma(z)) ; sigma(z) = 1/(1+exp(-z))
// element (x, ts): ts==1 -> ALPHA * g(x) ; ts==0 -> (1-ALPHA) * g(-x)
__device__ __forceinline__ float g_of(float z) {
    float e   = __expf(-z);
    float u   = 1.f + e;
    float pt  = __builtin_amdgcn_rcpf(u);   // sigma(z)
    float bce = __logf(u);                  // -log sigma(z)
    float om  = e * pt;                     // 1 - sigma(z), no cancellation
    return om * om * bce;
}

__global__ __launch_bounds__(THREADS) void focal_partial(
    const float4* __restrict__ in,     // float4 = 2 positions (x=c0,y=c1,z=c0,w=c1)
    const int4*   __restrict__ tgt,    // int4   = 4 positions
    float*        __restrict__ partial)
{
    const unsigned tid = blockIdx.x * (unsigned)THREADS + threadIdx.x;

    float acc_t = 0.f;   // true-class terms  (weight 0.25)
    float acc_f = 0.f;   // false-class terms (weight 0.75)

    auto compute = [&](const float4& v0, const float4& v1, const int4& t4) {
        const float x0[4] = {v0.x, v0.z, v1.x, v1.z};   // class-0 logits
        const float x1[4] = {v0.y, v0.w, v1.y, v1.w};   // class-1 logits
        const int   tt[4] = {t4.x, t4.y, t4.z, t4.w};
#pragma unroll
        for (int p = 0; p < 4; ++p) {
            bool  one = tt[p] != 0;
            float xt  = one ? x1[p] : x0[p];
            float xf  = one ? x0[p] : x1[p];
            acc_t += g_of(xt);
            acc_f += g_of(-xf);
        }
    };

    // depth-2 software pipeline with NAMED register sets (static everywhere)
    float4 a0, a1, b0, b1;
    int4   at4, bt4;

    a0  = in[2u * tid];
    a1  = in[2u * tid + 1u];
    at4 = tgt[tid];

#pragma unroll
    for (int i = 0; i < ITERS; ++i) {
        if ((i & 1) == 0) {
            if (i + 1 < ITERS) {               // prefetch i+1 into B
                unsigned qn = tid + (unsigned)(i + 1) * STRIDE;
                b0  = in[2u * qn];
                b1  = in[2u * qn + 1u];
                bt4 = tgt[qn];
            }
            compute(a0, a1, at4);
        } else {
            if (i + 1 < ITERS) {               // prefetch i+1 into A
                unsigned qn = tid + (unsigned)(i + 1) * STRIDE;
                a0  = in[2u * qn];
                a1  = in[2u * qn + 1u];
                at4 = tgt[qn];
            }
            compute(b0, b1, bt4);
        }
    }

    float acc = 0.25f * acc_t + 0.75f * acc_f;

    // wave (64-lane) reduction
#pragma unroll
    for (int off = 32; off > 0; off >>= 1)
        acc += __shfl_down(acc, off, 64);

    __shared__ float sm[THREADS / 64];
    const int lane = threadIdx.x & 63;
    const int wid  = threadIdx.x >> 6;
    if (lane == 0) sm[wid] = acc;
    __syncthreads();
    if (threadIdx.x == 0) {
        float s = 0.f;
#pragma unroll
        for (int w = 0; w < THREADS / 64; ++w) s += sm[w];
        partial[blockIdx.x] = s;
    }
}

__global__ __launch_bounds__(256) void focal_final(
    const float4* __restrict__ partial4,   // 2048 floats = 512 float4
    float*        __restrict__ out)
{
    float acc = 0.f;
#pragma unroll
    for (int r = 0; r < 2; ++r) {
        int i = r * 256 + threadIdx.x;
        if (i < BLOCKS / 4) {
            float4 p = partial4[i];
            acc += (p.x + p.y) + (p.z + p.w);
        }
    }
#pragma unroll
    for (int off = 32; off > 0; off >>= 1)
        acc += __shfl_down(acc, off, 64);

    __shared__ float sm[4];
    const int lane = threadIdx.x & 63;
    const int wid  = threadIdx.x >> 6;
    if (lane == 0) sm[wid] = acc;
    __syncthreads();
    if (threadIdx.x == 0) {
        float s = sm[0] + sm[1] + sm[2] + sm[3];
        out[0] = s * (1.0f / (2.0f * (float)NPOS));  // mean over B*T*2 elements
    }
}

extern "C" void kernel_launch(void* const* d_in, const int* in_sizes, int n_in,
                              void* d_out, int out_size, void* d_ws, size_t ws_size,
                              hipStream_t stream) {
    const float4* in  = (const float4*)d_in[0];
    const int4*   tgt = (const int4*)d_in[1];
    float* partial    = (float*)d_ws;
    float* out        = (float*)d_out;

    focal_partial<<<BLOCKS, THREADS, 0, stream>>>(in, tgt, partial);
    focal_final<<<1, 256, 0, stream>>>((const float4*)partial, out);
}